// Round 11
// baseline (270.042 us; speedup 1.0000x reference)
//
#include <hip/hip_runtime.h>
#include <hip/hip_bf16.h>

// RelativeAttention B=2,N=1024,C=512,H=8,HD=64 — round 10: anti-phase stagger.
//  EXACT round-9 kernel + one change: co-resident block pairs (bid, bid+256)
//  are deliberately de-phased by ~8Kcy (s_sleep) so one block's HBM staging
//  overlaps the other's compute phases (measured r7/r9: in-phase blocks SUM
//  staging+compute = 33Kcy/joint-iter; anti-phase model = 20Kcy).
// ws: qh 2MB | kh 2MB | vhT 2MB | xpart 16MB | lsum 256KB | xb 4MB

typedef __attribute__((ext_vector_type(8))) short short8;
typedef __attribute__((ext_vector_type(4))) short short4v;
typedef __attribute__((ext_vector_type(4))) float f32x4;

#if defined(__has_builtin)
#  if __has_builtin(__builtin_amdgcn_mfma_f32_16x16x16bf16_1k)
#    define HAVE_MFMA16 1
#  endif
#endif
#ifndef HAVE_MFMA16
#  define HAVE_MFMA16 0
#endif

__device__ __forceinline__ unsigned short f2b(float f) {
    union { float f; unsigned u; } v; v.f = f;
    unsigned r = (v.u + 0x7FFF + ((v.u >> 16) & 1)) >> 16;   // RNE
    return (unsigned short)r;
}

// v_cvt_pk_bf16_f32: dst = [bf16(b) | bf16(a)] (RNE), 1 VALU op
__device__ __forceinline__ unsigned cvt_pk(float a, float b) {
    unsigned r;
    asm("v_cvt_pk_bf16_f32 %0, %1, %2" : "=v"(r) : "v"(a), "v"(b));
    return r;
}

// ---------------------------------------------------------------------------
// GEMM: Y = X[2048,512] @ W[512,512]   (unchanged)
// ---------------------------------------------------------------------------
template <int MODE>
__global__ __launch_bounds__(256) void gemm512(
    const float* __restrict__ X, const float* __restrict__ W,
    const float* __restrict__ bias, float* __restrict__ Yf,
    unsigned short* __restrict__ Ybf, float scale)
{
    __shared__ float As[32][68];
    __shared__ float Bs[32][68];
    __shared__ float Ts[(MODE == 2) ? 64 : 1][65];
    const int t  = threadIdx.x;
    const int tx = t & 15, ty = t >> 4;
    const int m0 = blockIdx.x * 64;
    const int n0 = blockIdx.y * 64;

    float acc[4][4] = {};

    for (int k0 = 0; k0 < 512; k0 += 32) {
        #pragma unroll
        for (int l = 0; l < 2; l++) {
            int qi = t + l * 256;
            int r = qi >> 3, q = qi & 7;
            float4 av = *reinterpret_cast<const float4*>(
                X + (size_t)(m0 + r) * 512 + k0 + q * 4);
            As[q * 4 + 0][r] = av.x; As[q * 4 + 1][r] = av.y;
            As[q * 4 + 2][r] = av.z; As[q * 4 + 3][r] = av.w;
        }
        #pragma unroll
        for (int l = 0; l < 2; l++) {
            int qi = t + l * 256;
            int kk = qi >> 4, q = qi & 15;
            *reinterpret_cast<float4*>(&Bs[kk][q * 4]) =
                *reinterpret_cast<const float4*>(
                    W + (size_t)(k0 + kk) * 512 + n0 + q * 4);
        }
        __syncthreads();
        #pragma unroll
        for (int kk = 0; kk < 32; kk++) {
            float4 a4 = *reinterpret_cast<const float4*>(&As[kk][ty * 4]);
            float4 b4 = *reinterpret_cast<const float4*>(&Bs[kk][tx * 4]);
            float av[4] = {a4.x, a4.y, a4.z, a4.w};
            float bv[4] = {b4.x, b4.y, b4.z, b4.w};
            #pragma unroll
            for (int ii = 0; ii < 4; ii++)
                #pragma unroll
                for (int jj = 0; jj < 4; jj++)
                    acc[ii][jj] = fmaf(av[ii], bv[jj], acc[ii][jj]);
        }
        __syncthreads();
    }

    if (MODE == 0) {
        const int h = n0 >> 6;
        #pragma unroll
        for (int ii = 0; ii < 4; ii++) {
            int m = m0 + ty * 4 + ii;
            int bb = m >> 10, nn = m & 1023;
            ushort4 o;
            o.x = f2b(acc[ii][0] * scale); o.y = f2b(acc[ii][1] * scale);
            o.z = f2b(acc[ii][2] * scale); o.w = f2b(acc[ii][3] * scale);
            *reinterpret_cast<ushort4*>(
                Ybf + ((size_t)((bb * 8 + h) * 1024 + nn)) * 64 + tx * 4) = o;
        }
    } else if (MODE == 1) {
        float4 bv = *reinterpret_cast<const float4*>(bias + n0 + tx * 4);
        #pragma unroll
        for (int ii = 0; ii < 4; ii++) {
            int m = m0 + ty * 4 + ii;
            float4 o;
            o.x = acc[ii][0] + bv.x; o.y = acc[ii][1] + bv.y;
            o.z = acc[ii][2] + bv.z; o.w = acc[ii][3] + bv.w;
            *reinterpret_cast<float4*>(Yf + (size_t)m * 512 + n0 + tx * 4) = o;
        }
    } else {
        #pragma unroll
        for (int ii = 0; ii < 4; ii++)
            #pragma unroll
            for (int jj = 0; jj < 4; jj++)
                Ts[ty * 4 + ii][tx * 4 + jj] = acc[ii][jj];
        __syncthreads();
        const int h = n0 >> 6;
        const int bb = m0 >> 10, nn = m0 & 1023;
        const int rc = t >> 2, jc = t & 3;
        unsigned short tmp[16];
        #pragma unroll
        for (int q = 0; q < 16; q++) tmp[q] = f2b(Ts[jc * 16 + q][rc]);
        unsigned short* dst = Ybf + (((size_t)(bb * 8 + h) * 64 + rc) << 10) + nn + jc * 16;
        *reinterpret_cast<short8*>(dst)     = *reinterpret_cast<short8*>(&tmp[0]);
        *reinterpret_cast<short8*>(dst + 8) = *reinterpret_cast<short8*>(&tmp[8]);
    }
}

// ---------------------------------------------------------------------------
// attn: grid 512 = b(2) x itile(64) x jsplit(4); 512 thr = 8 waves = heads
// ---------------------------------------------------------------------------
__global__ __launch_bounds__(512, 4) void attn_mfma(
    const unsigned short* __restrict__ qhg, const unsigned short* __restrict__ khg,
    const unsigned short* __restrict__ vtg, const float* __restrict__ rpb,
    const float* __restrict__ mask, float* __restrict__ xpart,
    float* __restrict__ lsump)
{
    __shared__ unsigned short rpb_s[16][16][72]; // [i][j][c]  36.9KB
    __shared__ unsigned short q1[8][16][72];     // [h][i][c]  18.4KB
    __shared__ unsigned short P[8][16][40];      // [h][i][j] j16..39 ZERO, 10.2KB
    __shared__ float S2s[16][8][17];             // [i][h][j]   8.7KB

    const int bid = blockIdx.x;
    const int js = bid & 3, it = (bid >> 2) & 63, b = bid >> 8;
    const int i0 = it * 16, jb = js * 256;
    const int t = threadIdx.x, w = t >> 6, l = t & 63;
    const int lg = l >> 4, l16 = l & 15;

    // ---- anti-phase stagger: co-resident pair = (bid, bid+256) (XCD rr) ----
    // Delay the upper half ~8Kcy so its staging overlaps the peer's compute.
    if ((bid >> 8) & 1) {
        #pragma unroll 1
        for (int s = 0; s < 16; ++s) __builtin_amdgcn_s_sleep(8);  // 16*512cy
    }

    const int sj = (t >> 3) & 15, sc = (t & 7) * 8, sib = t >> 7;
    const float* rpbb = rpb + ((size_t)(b * 1024 + i0) << 16);
    const unsigned short* khb = khg + ((size_t)(b * 8 + w) << 16);
    const unsigned short* vtb = vtg + ((size_t)(b * 8 + w) << 16);

    // ---- prologue: stage q tile, zero P (pad needed only for fallback) ----
    {
        int h = t >> 6, i = (t >> 2) & 15, c = (t & 3) * 16;
        const short8* src = reinterpret_cast<const short8*>(
            qhg + (((size_t)(b * 8 + h) * 1024 + i0 + i) << 6) + c);
        *reinterpret_cast<short8*>(&q1[h][i][c])     = src[0];
        *reinterpret_cast<short8*>(&q1[h][i][c + 8]) = src[1];
    }
    {
        unsigned short* P1 = &P[0][0][0];
        #pragma unroll
        for (int r = 0; r < 10; ++r) P1[t + 512 * r] = 0;   // 5120 = 512*10
    }
    float mrow[4];
    #pragma unroll
    for (int r = 0; r < 4; r++) mrow[r] = mask[b * 1024 + i0 + lg * 4 + r];

    __syncthreads();   // q1 + P-zero visible

    short8 a1[2];   // S1 A-frag: q[w][i=l16][c=8lg+e (+32)] — loop-invariant
    a1[0] = *reinterpret_cast<const short8*>(&q1[w][l16][8 * lg]);
    a1[1] = *reinterpret_cast<const short8*>(&q1[w][l16][32 + 8 * lg]);

    const int jo = (lg < 2) ? 8 * lg : 0;   // fallback zero-pad clamp
    const int ro = jo;
    (void)ro;

    f32x4 x1[4];
    #pragma unroll
    for (int cs = 0; cs < 4; cs++) x1[cs] = 0.0f;
    f32x4 x2[2][4];
    #pragma unroll
    for (int il = 0; il < 2; il++)
        #pragma unroll
        for (int cg = 0; cg < 4; cg++) x2[il][cg] = 0.0f;
    float lsum[4] = {0.f, 0.f, 0.f, 0.f};

    for (int jt = 0; jt < 16; ++jt) {
        const int j0 = jb + jt * 16;
        __syncthreads();                         // barA: prev readers done

        // bq (S2 B-frag) from q1 LDS: q[head=l16&7][i=2w+il][c]
        short8 bq[2][2];
        #pragma unroll
        for (int il = 0; il < 2; ++il) {
            bq[il][0] = *reinterpret_cast<const short8*>(
                &q1[l16 & 7][2 * w + il][8 * lg]);
            bq[il][1] = *reinterpret_cast<const short8*>(
                &q1[l16 & 7][2 * w + il][32 + 8 * lg]);
        }
        float mj = mask[b * 1024 + j0 + l16];

        // ---- stage rpb tile [16i][16j][64c] f32 -> bf16 (cvt_pk) ----
        #pragma unroll
        for (int itr = 0; itr < 4; ++itr) {
            const float4* s_ = reinterpret_cast<const float4*>(
                rpbb + ((size_t)(sib + 4 * itr) << 16) + (size_t)(j0 + sj) * 64 + sc);
            float4 ua = s_[0], ub = s_[1];
            uint4 pk;
            pk.x = cvt_pk(ua.x, ua.y); pk.y = cvt_pk(ua.z, ua.w);
            pk.z = cvt_pk(ub.x, ub.y); pk.w = cvt_pk(ub.z, ub.w);
            *reinterpret_cast<uint4*>(&rpb_s[sib + 4 * itr][sj][sc]) = pk;
        }
        __syncthreads();                         // barB: tile staged

        // ---- S1 = QK^T : D[16i x 16j], K=64 (2x K=32 mfma) ----
        f32x4 C1; C1 = 0.0f;
        {
            const unsigned short* kp = khb + (((size_t)(j0 + l16)) << 6) + 8 * lg;
            short8 kb0 = *reinterpret_cast<const short8*>(kp);
            short8 kb1 = *reinterpret_cast<const short8*>(kp + 32);
            C1 = __builtin_amdgcn_mfma_f32_16x16x32_bf16(a1[0], kb0, C1, 0, 0, 0);
            C1 = __builtin_amdgcn_mfma_f32_16x16x32_bf16(a1[1], kb1, C1, 0, 0, 0);
        }
        // ---- S2^T = rpb(A) @ q(B) : D[16j x 8h] per i, K=64 ----
        #pragma unroll
        for (int il = 0; il < 2; ++il) {
            int i = 2 * w + il;
            f32x4 D2; D2 = 0.0f;
            #pragma unroll
            for (int ch = 0; ch < 2; ++ch) {
                short8 ar = *reinterpret_cast<const short8*>(
                    &rpb_s[i][l16][ch * 32 + 8 * lg]);
                D2 = __builtin_amdgcn_mfma_f32_16x16x32_bf16(ar, bq[il][ch], D2, 0, 0, 0);
            }
            if (l16 < 8) {                        // D: row=j=4lg+r, col=h=l16
                #pragma unroll
                for (int r = 0; r < 4; ++r)
                    S2s[i][l16][4 * lg + r] = D2[r];
            }
        }
        __syncthreads();                         // barC: S2s ready

        // ---- P = exp(S1 + S2 + pairmask) ----
        #pragma unroll
        for (int r = 0; r < 4; ++r) {
            int ir = lg * 4 + r;
            float mi = mrow[r];
            float pm = (fmaxf(mi, mj) < 0.f) ? 0.f : fminf(mi, mj);
            float s = C1[r] + S2s[ir][w][l16] + pm;
            float p = __expf(s);                  // bounded logits; -1e4 -> 0
            lsum[r] += p;
            P[w][ir][l16] = f2b(p);
        }
        __syncthreads();                         // barD: P ready

#if HAVE_MFMA16
        // ---- X1 += P @ vhT : D[16i x 64c], K=16 (exact j-tile) ----
        {
            short4v pa = *reinterpret_cast<const short4v*>(&P[w][l16][4 * lg]);
            #pragma unroll
            for (int cs = 0; cs < 4; ++cs) {
                short4v vb = *reinterpret_cast<const short4v*>(
                    vtb + ((size_t)(cs * 16 + l16) << 10) + j0 + 4 * lg);
                x1[cs] = __builtin_amdgcn_mfma_f32_16x16x16bf16_1k(pa, vb, x1[cs], 0, 0, 0);
            }
        }
        // ---- X2 += P(A) @ rpb(B) : D[8h x 16c] per i, K=16 ----
        #pragma unroll
        for (int il = 0; il < 2; ++il) {
            int i = 2 * w + il;
            short4v pa2 = *reinterpret_cast<const short4v*>(&P[l16 & 7][i][4 * lg]);
            #pragma unroll
            for (int cg = 0; cg < 4; ++cg) {
                short4v bb;
                #pragma unroll
                for (int e = 0; e < 4; ++e)
                    bb[e] = (short)rpb_s[i][4 * lg + e][cg * 16 + l16];
                x2[il][cg] = __builtin_amdgcn_mfma_f32_16x16x16bf16_1k(pa2, bb, x2[il][cg], 0, 0, 0);
            }
        }
#else
        // ---- fallback: r5 zero-padded K=32 path ----
        {
            short8 pa = *reinterpret_cast<const short8*>(&P[w][l16][8 * lg]);
            #pragma unroll
            for (int cs = 0; cs < 4; ++cs) {
                short8 vb = *reinterpret_cast<const short8*>(
                    vtb + ((size_t)(cs * 16 + l16) << 10) + j0 + jo);
                x1[cs] = __builtin_amdgcn_mfma_f32_16x16x32_bf16(pa, vb, x1[cs], 0, 0, 0);
            }
        }
        #pragma unroll
        for (int il = 0; il < 2; ++il) {
            int i = 2 * w + il;
            short8 pa2 = *reinterpret_cast<const short8*>(&P[l16 & 7][i][8 * lg]);
            #pragma unroll
            for (int cg = 0; cg < 4; ++cg) {
                short8 bb;
                #pragma unroll
                for (int e = 0; e < 8; ++e)
                    bb[e] = (short)rpb_s[i][ro + e][cg * 16 + l16];
                x2[il][cg] = __builtin_amdgcn_mfma_f32_16x16x32_bf16(pa2, bb, x2[il][cg], 0, 0, 0);
            }
        }
#endif
    }

    // ---- epilogue ----
    #pragma unroll
    for (int r = 0; r < 4; ++r) {
        float v = lsum[r];
        v += __shfl_xor(v, 1, 64); v += __shfl_xor(v, 2, 64);
        v += __shfl_xor(v, 4, 64); v += __shfl_xor(v, 8, 64);
        lsum[r] = v;
    }

    __syncthreads();   // all rpb_s reads done; reuse rpb_s as x2 redistribute buf
    float* x2s = reinterpret_cast<float*>(&rpb_s[0][0][0]);   // [16i][8h][64c]
    if (lg < 2) {
        #pragma unroll
        for (int il = 0; il < 2; ++il)
            #pragma unroll
            for (int cg = 0; cg < 4; ++cg)
                #pragma unroll
                for (int r = 0; r < 4; ++r)
                    x2s[((2 * w + il) * 8 + 4 * lg + r) * 64 + cg * 16 + l16] =
                        x2[il][cg][r];
    }
    __syncthreads();

    #pragma unroll
    for (int cs = 0; cs < 4; ++cs)
        #pragma unroll
        for (int r = 0; r < 4; ++r) {
            int ir = lg * 4 + r;
            float val = x1[cs][r] + x2s[(ir * 8 + w) * 64 + cs * 16 + l16];
            xpart[((size_t)js << 20) + ((size_t)(b * 1024 + i0 + ir)) * 512
                  + w * 64 + cs * 16 + l16] = val;
        }
    if (l16 == 0) {
        #pragma unroll
        for (int r = 0; r < 4; ++r)
            lsump[((size_t)js << 14) + (b * 8 + w) * 1024 + i0 + lg * 4 + r] = lsum[r];
    }
}

// ---------------------------------------------------------------------------
__global__ __launch_bounds__(256) void combine(
    const float* __restrict__ xpart, const float* __restrict__ lsump,
    float* __restrict__ xb)
{
    int idx4 = blockIdx.x * 256 + threadIdx.x;
    size_t base = (size_t)idx4 * 4;
    int row = (int)(base >> 9), col = (int)(base & 511);
    int bb = row >> 10, n = row & 1023, h = col >> 6;
    float ax = 0.f, ay = 0.f, az = 0.f, aw = 0.f, ls = 0.f;
    #pragma unroll
    for (int js = 0; js < 4; ++js) {
        float4 v = *reinterpret_cast<const float4*>(xpart + ((size_t)js << 20) + base);
        ax += v.x; ay += v.y; az += v.z; aw += v.w;
        ls += lsump[(js << 14) + (bb * 8 + h) * 1024 + n];
    }
    float inv = 1.f / ls;
    float4 o; o.x = ax * inv; o.y = ay * inv; o.z = az * inv; o.w = aw * inv;
    *reinterpret_cast<float4*>(xb + base) = o;
}

// ---------------------------------------------------------------------------
extern "C" void kernel_launch(void* const* d_in, const int* in_sizes, int n_in,
                              void* d_out, int out_size, void* d_ws, size_t ws_size,
                              hipStream_t stream)
{
    (void)in_sizes; (void)n_in; (void)out_size; (void)ws_size;
    const float* q    = (const float*)d_in[0];
    const float* k    = (const float*)d_in[1];
    const float* v    = (const float*)d_in[2];
    const float* rpb  = (const float*)d_in[3];
    const float* mask = (const float*)d_in[4];
    const float* Wq   = (const float*)d_in[5];
    const float* Wk   = (const float*)d_in[6];
    const float* Wv   = (const float*)d_in[7];
    const float* Wp   = (const float*)d_in[8];
    const float* bp   = (const float*)d_in[9];
    float* out = (float*)d_out;

    unsigned short* qhb = (unsigned short*)d_ws;     // bf16 [2,8,1024,64]
    unsigned short* khb = qhb + 1048576;
    unsigned short* vtb = khb + 1048576;             // bf16 [2,8,64,1024]
    float* xpart = (float*)(vtb + 1048576);          // [4][2048][512]
    float* lsump = xpart + 4194304;                  // [4][16384]
    float* xb    = lsump + 65536;                    // [2048][512]

    dim3 gg(32, 8, 1);
    gemm512<0><<<gg, 256, 0, stream>>>(q, Wq, nullptr, nullptr, qhb, 0.125f);
    gemm512<0><<<gg, 256, 0, stream>>>(k, Wk, nullptr, nullptr, khb, 1.0f);
    gemm512<2><<<gg, 256, 0, stream>>>(v, Wv, nullptr, nullptr, vtb, 1.0f);

    attn_mfma<<<512, 512, 0, stream>>>(qhb, khb, vtb, rpb, mask, xpart, lsump);

    combine<<<1024, 256, 0, stream>>>(xpart, lsump, xb);

    gemm512<1><<<gg, 256, 0, stream>>>(xb, Wp, bp, out, nullptr, 1.0f);
}

// Round 12
// 257.482 us; speedup vs baseline: 1.0488x; 1.0488x over previous
//
#include <hip/hip_runtime.h>
#include <hip/hip_bf16.h>

// RelativeAttention B=2,N=1024,C=512,H=8,HD=64 — round 11: clean-FIFO pipeline.
//  attn: grid 256 = b(2) x itile(64) x jsplit(2); 1 block/CU, 8 waves.
//  ALL in-loop global loads (rpb, kh tile, vtb tile) issued as one batch at
//  iter top for t+1, consumed at top of t+1 in the SAME order -> compiler's
//  automatic waits are counted vmcnt(N), loads stay in flight across the 4
//  raw lgkm-only barriers (no __syncthreads vmcnt0 drain in the loop).
//  kh/vtb read from LDS tiles; q fragments (a1,bq) hoisted (loop-invariant);
//  mask in LDS. LDS 152.5KB.
// ws: qh 2MB | kh 2MB | vhT 2MB | xpart 8MB | lsum 128KB | xb 4MB

typedef __attribute__((ext_vector_type(8))) short short8;
typedef __attribute__((ext_vector_type(4))) short short4v;
typedef __attribute__((ext_vector_type(4))) float f32x4;

#if defined(__has_builtin)
#  if __has_builtin(__builtin_amdgcn_mfma_f32_16x16x16bf16_1k)
#    define HAVE_MFMA16 1
#  endif
#endif
#ifndef HAVE_MFMA16
#  define HAVE_MFMA16 0
#endif

__device__ __forceinline__ unsigned short f2b(float f) {
    union { float f; unsigned u; } v; v.f = f;
    unsigned r = (v.u + 0x7FFF + ((v.u >> 16) & 1)) >> 16;   // RNE
    return (unsigned short)r;
}

__device__ __forceinline__ unsigned cvt_pk(float a, float b) {
    unsigned r;
    asm("v_cvt_pk_bf16_f32 %0, %1, %2" : "=v"(r) : "v"(a), "v"(b));
    return r;
}

// lgkm-drain + raw barrier: LDS ordered; global loads NOT drained.
#define LGKM0_BAR()                                            \
    do {                                                       \
        asm volatile("s_waitcnt lgkmcnt(0)" ::: "memory");     \
        __builtin_amdgcn_s_barrier();                          \
        asm volatile("" ::: "memory");                         \
    } while (0)

// ---------------------------------------------------------------------------
// GEMM: Y = X[2048,512] @ W[512,512]   (unchanged)
// ---------------------------------------------------------------------------
template <int MODE>
__global__ __launch_bounds__(256) void gemm512(
    const float* __restrict__ X, const float* __restrict__ W,
    const float* __restrict__ bias, float* __restrict__ Yf,
    unsigned short* __restrict__ Ybf, float scale)
{
    __shared__ float As[32][68];
    __shared__ float Bs[32][68];
    __shared__ float Ts[(MODE == 2) ? 64 : 1][65];
    const int t  = threadIdx.x;
    const int tx = t & 15, ty = t >> 4;
    const int m0 = blockIdx.x * 64;
    const int n0 = blockIdx.y * 64;

    float acc[4][4] = {};

    for (int k0 = 0; k0 < 512; k0 += 32) {
        #pragma unroll
        for (int l = 0; l < 2; l++) {
            int qi = t + l * 256;
            int r = qi >> 3, q = qi & 7;
            float4 av = *reinterpret_cast<const float4*>(
                X + (size_t)(m0 + r) * 512 + k0 + q * 4);
            As[q * 4 + 0][r] = av.x; As[q * 4 + 1][r] = av.y;
            As[q * 4 + 2][r] = av.z; As[q * 4 + 3][r] = av.w;
        }
        #pragma unroll
        for (int l = 0; l < 2; l++) {
            int qi = t + l * 256;
            int kk = qi >> 4, q = qi & 15;
            *reinterpret_cast<float4*>(&Bs[kk][q * 4]) =
                *reinterpret_cast<const float4*>(
                    W + (size_t)(k0 + kk) * 512 + n0 + q * 4);
        }
        __syncthreads();
        #pragma unroll
        for (int kk = 0; kk < 32; kk++) {
            float4 a4 = *reinterpret_cast<const float4*>(&As[kk][ty * 4]);
            float4 b4 = *reinterpret_cast<const float4*>(&Bs[kk][tx * 4]);
            float av[4] = {a4.x, a4.y, a4.z, a4.w};
            float bv[4] = {b4.x, b4.y, b4.z, b4.w};
            #pragma unroll
            for (int ii = 0; ii < 4; ii++)
                #pragma unroll
                for (int jj = 0; jj < 4; jj++)
                    acc[ii][jj] = fmaf(av[ii], bv[jj], acc[ii][jj]);
        }
        __syncthreads();
    }

    if (MODE == 0) {
        const int h = n0 >> 6;
        #pragma unroll
        for (int ii = 0; ii < 4; ii++) {
            int m = m0 + ty * 4 + ii;
            int bb = m >> 10, nn = m & 1023;
            ushort4 o;
            o.x = f2b(acc[ii][0] * scale); o.y = f2b(acc[ii][1] * scale);
            o.z = f2b(acc[ii][2] * scale); o.w = f2b(acc[ii][3] * scale);
            *reinterpret_cast<ushort4*>(
                Ybf + ((size_t)((bb * 8 + h) * 1024 + nn)) * 64 + tx * 4) = o;
        }
    } else if (MODE == 1) {
        float4 bv = *reinterpret_cast<const float4*>(bias + n0 + tx * 4);
        #pragma unroll
        for (int ii = 0; ii < 4; ii++) {
            int m = m0 + ty * 4 + ii;
            float4 o;
            o.x = acc[ii][0] + bv.x; o.y = acc[ii][1] + bv.y;
            o.z = acc[ii][2] + bv.z; o.w = acc[ii][3] + bv.w;
            *reinterpret_cast<float4*>(Yf + (size_t)m * 512 + n0 + tx * 4) = o;
        }
    } else {
        #pragma unroll
        for (int ii = 0; ii < 4; ii++)
            #pragma unroll
            for (int jj = 0; jj < 4; jj++)
                Ts[ty * 4 + ii][tx * 4 + jj] = acc[ii][jj];
        __syncthreads();
        const int h = n0 >> 6;
        const int bb = m0 >> 10, nn = m0 & 1023;
        const int rc = t >> 2, jc = t & 3;
        unsigned short tmp[16];
        #pragma unroll
        for (int q = 0; q < 16; q++) tmp[q] = f2b(Ts[jc * 16 + q][rc]);
        unsigned short* dst = Ybf + (((size_t)(bb * 8 + h) * 64 + rc) << 10) + nn + jc * 16;
        *reinterpret_cast<short8*>(dst)     = *reinterpret_cast<short8*>(&tmp[0]);
        *reinterpret_cast<short8*>(dst + 8) = *reinterpret_cast<short8*>(&tmp[8]);
    }
}

// ---------------------------------------------------------------------------
// attn: grid 256 = b(2) x itile(64) x jsplit(2); 512 thr = 8 waves = heads
// ---------------------------------------------------------------------------
__global__ __launch_bounds__(512, 2) void attn_mfma(
    const unsigned short* __restrict__ qhg, const unsigned short* __restrict__ khg,
    const unsigned short* __restrict__ vtg, const float* __restrict__ rpb,
    const float* __restrict__ mask, float* __restrict__ xpart,
    float* __restrict__ lsump)
{
    __shared__ unsigned short rpb_s[2][16][16][72]; // dbuf rpb tile   73728B
    __shared__ unsigned short khs[8][16][72];       // kh tile [h][j][c] 18432B
    __shared__ unsigned short vts[8][64][24];       // vt tile [h][c][j] 24576B
    __shared__ unsigned short q1[8][16][72];        // prologue q       18432B
    __shared__ unsigned short P[8][16][40];         // j16..39 ZERO     10240B
    __shared__ float S2s[16][8][17];                //                   8704B
    __shared__ float mask_s[512];                   //                   2048B

    const int bid = blockIdx.x;
    const int js = bid & 1, it = (bid >> 1) & 63, b = bid >> 7;
    const int i0 = it * 16, jb = js * 512;
    const int t = threadIdx.x, w = t >> 6, l = t & 63;
    const int lg = l >> 4, l16 = l & 15;

    // staging thread maps
    const int sj = (t >> 3) & 15, sc = (t & 7) * 8, sib = t >> 7;      // rpb
    const int kh_h = t >> 6, kh_j = (t >> 2) & 15, kh_c = (t & 3) * 16; // kh
    const int vt_h = t >> 6, vt_c = t & 63;                             // vtb

    const float* rpbb = rpb + ((size_t)(b * 1024 + i0) << 16);

#define RPB_ISSUE(PF, J0)                                                      \
    _Pragma("unroll")                                                          \
    for (int itr = 0; itr < 4; ++itr) {                                        \
        const float4* s_ = reinterpret_cast<const float4*>(                    \
            rpbb + ((size_t)(sib + 4 * itr) << 16) +                           \
            (size_t)((J0) + sj) * 64 + sc);                                    \
        PF[2 * itr] = s_[0]; PF[2 * itr + 1] = s_[1];                          \
    }

#define RPB_WRITE(PF, BUF)                                                     \
    _Pragma("unroll")                                                          \
    for (int itr = 0; itr < 4; ++itr) {                                        \
        float4 ua = PF[2 * itr], ub = PF[2 * itr + 1];                         \
        uint4 pk;                                                              \
        pk.x = cvt_pk(ua.x, ua.y); pk.y = cvt_pk(ua.z, ua.w);                  \
        pk.z = cvt_pk(ub.x, ub.y); pk.w = cvt_pk(ub.z, ub.w);                  \
        *reinterpret_cast<uint4*>(&rpb_s[BUF][sib + 4 * itr][sj][sc]) = pk;    \
    }

#define KH_ISSUE(KP, J0)                                                       \
    {                                                                          \
        const unsigned short* p_ = khg + ((size_t)(b * 8 + kh_h) << 16) +      \
            (size_t)((J0) + kh_j) * 64 + kh_c;                                 \
        KP[0] = *reinterpret_cast<const short8*>(p_);                          \
        KP[1] = *reinterpret_cast<const short8*>(p_ + 8);                      \
    }

#define KH_WRITE(KP)                                                           \
    {                                                                          \
        *reinterpret_cast<short8*>(&khs[kh_h][kh_j][kh_c])     = KP[0];        \
        *reinterpret_cast<short8*>(&khs[kh_h][kh_j][kh_c + 8]) = KP[1];        \
    }

#define VT_ISSUE(VP, J0)                                                       \
    {                                                                          \
        const unsigned short* p_ = vtg + ((size_t)(b * 8 + vt_h) << 16) +      \
            ((size_t)vt_c << 10) + (J0);                                       \
        VP[0] = *reinterpret_cast<const short8*>(p_);                          \
        VP[1] = *reinterpret_cast<const short8*>(p_ + 8);                      \
    }

#define VT_WRITE(VP)                                                           \
    {                                                                          \
        *reinterpret_cast<short8*>(&vts[vt_h][vt_c][0]) = VP[0];               \
        *reinterpret_cast<short8*>(&vts[vt_h][vt_c][8]) = VP[1];               \
    }

    // ---- prologue: q tile, mask row, zero P; then issue batch(0) ----
    {
        int h = t >> 6, i = (t >> 2) & 15, c = (t & 3) * 16;
        const short8* src = reinterpret_cast<const short8*>(
            qhg + (((size_t)(b * 8 + h) * 1024 + i0 + i) << 6) + c);
        *reinterpret_cast<short8*>(&q1[h][i][c])     = src[0];
        *reinterpret_cast<short8*>(&q1[h][i][c + 8]) = src[1];
    }
    if (t < 128) {
        *reinterpret_cast<float4*>(&mask_s[t * 4]) =
            *reinterpret_cast<const float4*>(&mask[b * 1024 + jb + t * 4]);
    }
    {
        unsigned short* P1 = &P[0][0][0];
        #pragma unroll
        for (int r = 0; r < 10; ++r) P1[t + 512 * r] = 0;   // 5120 = 512*10
    }
    float mrow[4];
    #pragma unroll
    for (int r = 0; r < 4; r++) mrow[r] = mask[b * 1024 + i0 + lg * 4 + r];

    float4 pfA[8], pfB[8];
    short8 kpfA[2], kpfB[2], vpfA[2], vpfB[2];
    RPB_ISSUE(pfA, jb)
    KH_ISSUE(kpfA, jb)
    VT_ISSUE(vpfA, jb)

    LGKM0_BAR();   // q1/mask_s/P visible; batch(0) still in flight

    // hoisted loop-invariant q fragments
    short8 a1[2];
    a1[0] = *reinterpret_cast<const short8*>(&q1[w][l16][8 * lg]);
    a1[1] = *reinterpret_cast<const short8*>(&q1[w][l16][32 + 8 * lg]);
    short8 bq[2][2];
    #pragma unroll
    for (int il = 0; il < 2; ++il) {
        bq[il][0] = *reinterpret_cast<const short8*>(
            &q1[l16 & 7][2 * w + il][8 * lg]);
        bq[il][1] = *reinterpret_cast<const short8*>(
            &q1[l16 & 7][2 * w + il][32 + 8 * lg]);
    }

    const int jo = (lg < 2) ? 8 * lg : 0;   // K32-fallback zero-pad clamp
    const int ro = jo;
    (void)ro;

    f32x4 x1[4];
    #pragma unroll
    for (int cs = 0; cs < 4; cs++) x1[cs] = 0.0f;
    f32x4 x2[2][4];
    #pragma unroll
    for (int il = 0; il < 2; il++)
        #pragma unroll
        for (int cg = 0; cg < 4; cg++) x2[il][cg] = 0.0f;
    float lsum[4] = {0.f, 0.f, 0.f, 0.f};

#define ATTN_ITER(T, PFC, KPC, VPC, PFN, KPN, VPN)                             \
    {                                                                          \
        const int jt = (T);                                                    \
        const int cur = jt & 1;                                                \
        const int j0 = jb + jt * 16;                                           \
        /* issue batch(jt+1) FIRST (FIFO: newer than batch(jt)) */             \
        if (jt < 31) {                                                         \
            RPB_ISSUE(PFN, j0 + 16)                                            \
            KH_ISSUE(KPN, j0 + 16)                                             \
            VT_ISSUE(VPN, j0 + 16)                                             \
        }                                                                      \
        /* consume batch(jt) in issue order (counted vmcnt, auto) */           \
        RPB_WRITE(PFC, cur)                                                    \
        KH_WRITE(KPC)                                                          \
        VT_WRITE(VPC)                                                          \
        LGKM0_BAR();  /* bar1: staged tiles visible */                         \
        /* S1 = QK^T : D[16i x 16j], K=64, kh from LDS */                      \
        f32x4 C1; C1 = 0.0f;                                                   \
        {                                                                      \
            short8 kb0 = *reinterpret_cast<const short8*>(&khs[w][l16][8 * lg]); \
            short8 kb1 = *reinterpret_cast<const short8*>(&khs[w][l16][32 + 8 * lg]); \
            C1 = __builtin_amdgcn_mfma_f32_16x16x32_bf16(a1[0], kb0, C1, 0, 0, 0); \
            C1 = __builtin_amdgcn_mfma_f32_16x16x32_bf16(a1[1], kb1, C1, 0, 0, 0); \
        }                                                                      \
        /* S2^T = rpb(A) @ q(B) : D[16j x 8h] per i */                         \
        _Pragma("unroll")                                                      \
        for (int il = 0; il < 2; ++il) {                                       \
            int i = 2 * w + il;                                                \
            f32x4 D2; D2 = 0.0f;                                               \
            _Pragma("unroll")                                                  \
            for (int ch = 0; ch < 2; ++ch) {                                   \
                short8 ar = *reinterpret_cast<const short8*>(                  \
                    &rpb_s[cur][i][l16][ch * 32 + 8 * lg]);                    \
                D2 = __builtin_amdgcn_mfma_f32_16x16x32_bf16(ar, bq[il][ch], D2, 0, 0, 0); \
            }                                                                  \
            if (l16 < 8) {                                                     \
                _Pragma("unroll")                                              \
                for (int r = 0; r < 4; ++r)                                    \
                    S2s[i][l16][4 * lg + r] = D2[r];                           \
            }                                                                  \
        }                                                                      \
        LGKM0_BAR();  /* bar2: S2s ready */                                    \
        /* P = exp(S1 + S2 + pairmask) */                                      \
        {                                                                      \
            float mj = mask_s[jt * 16 + l16];                                  \
            _Pragma("unroll")                                                  \
            for (int r = 0; r < 4; ++r) {                                      \
                int ir = lg * 4 + r;                                           \
                float mi = mrow[r];                                            \
                float pm = (fmaxf(mi, mj) < 0.f) ? 0.f : fminf(mi, mj);        \
                float s = C1[r] + S2s[ir][w][l16] + pm;                        \
                float p = __expf(s);                                           \
                lsum[r] += p;                                                  \
                P[w][ir][l16] = f2b(p);                                        \
            }                                                                  \
        }                                                                      \
        LGKM0_BAR();  /* bar3: P ready */                                      \
        X1X2_BODY(cur)                                                         \
        LGKM0_BAR();  /* bar4: X reads done -> next-iter staging may overwrite */ \
    }

#if HAVE_MFMA16
#define X1X2_BODY(CUR)                                                         \
    {                                                                          \
        short4v pa = *reinterpret_cast<const short4v*>(&P[w][l16][4 * lg]);    \
        _Pragma("unroll")                                                      \
        for (int cs = 0; cs < 4; ++cs) {                                       \
            short4v vb = *reinterpret_cast<const short4v*>(                    \
                &vts[w][cs * 16 + l16][4 * lg]);                               \
            x1[cs] = __builtin_amdgcn_mfma_f32_16x16x16bf16_1k(pa, vb, x1[cs], 0, 0, 0); \
        }                                                                      \
    }                                                                          \
    _Pragma("unroll")                                                          \
    for (int il = 0; il < 2; ++il) {                                           \
        int i = 2 * w + il;                                                    \
        short4v pa2 = *reinterpret_cast<const short4v*>(&P[l16 & 7][i][4 * lg]); \
        _Pragma("unroll")                                                      \
        for (int cg = 0; cg < 4; ++cg) {                                       \
            short4v bb;                                                        \
            _Pragma("unroll")                                                  \
            for (int e = 0; e < 4; ++e)                                        \
                bb[e] = (short)rpb_s[CUR][i][4 * lg + e][cg * 16 + l16];       \
            x2[il][cg] = __builtin_amdgcn_mfma_f32_16x16x16bf16_1k(pa2, bb, x2[il][cg], 0, 0, 0); \
        }                                                                      \
    }
#else
#define X1X2_BODY(CUR)                                                         \
    {                                                                          \
        short8 pa = *reinterpret_cast<const short8*>(&P[w][l16][8 * lg]);      \
        _Pragma("unroll")                                                      \
        for (int cs = 0; cs < 4; ++cs) {                                       \
            short8 vb = *reinterpret_cast<const short8*>(                      \
                &vts[w][cs * 16 + l16][jo]);                                   \
            x1[cs] = __builtin_amdgcn_mfma_f32_16x16x32_bf16(pa, vb, x1[cs], 0, 0, 0); \
        }                                                                      \
    }                                                                          \
    _Pragma("unroll")                                                          \
    for (int il = 0; il < 2; ++il) {                                           \
        int i = 2 * w + il;                                                    \
        short8 pa2 = *reinterpret_cast<const short8*>(&P[l16 & 7][i][8 * lg]); \
        _Pragma("unroll")                                                      \
        for (int cg = 0; cg < 4; ++cg) {                                       \
            short8 bb;                                                         \
            _Pragma("unroll")                                                  \
            for (int e = 0; e < 8; ++e)                                        \
                bb[e] = (short)rpb_s[CUR][i][ro + e][cg * 16 + l16];           \
            x2[il][cg] = __builtin_amdgcn_mfma_f32_16x16x32_bf16(pa2, bb, x2[il][cg], 0, 0, 0); \
        }                                                                      \
    }
#endif

    for (int th = 0; th < 16; ++th) {
        ATTN_ITER(2 * th,     pfA, kpfA, vpfA, pfB, kpfB, vpfB)
        ATTN_ITER(2 * th + 1, pfB, kpfB, vpfB, pfA, kpfA, vpfA)
    }

    // ---- epilogue ----
    #pragma unroll
    for (int r = 0; r < 4; ++r) {
        float v = lsum[r];
        v += __shfl_xor(v, 1, 64); v += __shfl_xor(v, 2, 64);
        v += __shfl_xor(v, 4, 64); v += __shfl_xor(v, 8, 64);
        lsum[r] = v;
    }

    __syncthreads();   // loop done; reuse rpb_s as x2 redistribute buffer
    float* x2s = reinterpret_cast<float*>(&rpb_s[0][0][0][0]);  // [16i][8h][64c]
    if (lg < 2) {
        #pragma unroll
        for (int il = 0; il < 2; ++il)
            #pragma unroll
            for (int cg = 0; cg < 4; ++cg)
                #pragma unroll
                for (int r = 0; r < 4; ++r)
                    x2s[((2 * w + il) * 8 + 4 * lg + r) * 64 + cg * 16 + l16] =
                        x2[il][cg][r];
    }
    __syncthreads();

    #pragma unroll
    for (int cs = 0; cs < 4; ++cs)
        #pragma unroll
        for (int r = 0; r < 4; ++r) {
            int ir = lg * 4 + r;
            float val = x1[cs][r] + x2s[(ir * 8 + w) * 64 + cs * 16 + l16];
            xpart[((size_t)js << 20) + ((size_t)(b * 1024 + i0 + ir)) * 512
                  + w * 64 + cs * 16 + l16] = val;
        }
    if (l16 == 0) {
        #pragma unroll
        for (int r = 0; r < 4; ++r)
            lsump[((size_t)js << 14) + (b * 8 + w) * 1024 + i0 + lg * 4 + r] = lsum[r];
    }
#undef ATTN_ITER
#undef X1X2_BODY
#undef RPB_ISSUE
#undef RPB_WRITE
#undef KH_ISSUE
#undef KH_WRITE
#undef VT_ISSUE
#undef VT_WRITE
}

// ---------------------------------------------------------------------------
__global__ __launch_bounds__(256) void combine(
    const float* __restrict__ xpart, const float* __restrict__ lsump,
    float* __restrict__ xb)
{
    int idx4 = blockIdx.x * 256 + threadIdx.x;
    size_t base = (size_t)idx4 * 4;
    int row = (int)(base >> 9), col = (int)(base & 511);
    int bb = row >> 10, n = row & 1023, h = col >> 6;
    float ax = 0.f, ay = 0.f, az = 0.f, aw = 0.f, ls = 0.f;
    #pragma unroll
    for (int js = 0; js < 2; ++js) {
        float4 v = *reinterpret_cast<const float4*>(xpart + ((size_t)js << 20) + base);
        ax += v.x; ay += v.y; az += v.z; aw += v.w;
        ls += lsump[(js << 14) + (bb * 8 + h) * 1024 + n];
    }
    float inv = 1.f / ls;
    float4 o; o.x = ax * inv; o.y = ay * inv; o.z = az * inv; o.w = aw * inv;
    *reinterpret_cast<float4*>(xb + base) = o;
}

// ---------------------------------------------------------------------------
extern "C" void kernel_launch(void* const* d_in, const int* in_sizes, int n_in,
                              void* d_out, int out_size, void* d_ws, size_t ws_size,
                              hipStream_t stream)
{
    (void)in_sizes; (void)n_in; (void)out_size; (void)ws_size;
    const float* q    = (const float*)d_in[0];
    const float* k    = (const float*)d_in[1];
    const float* v    = (const float*)d_in[2];
    const float* rpb  = (const float*)d_in[3];
    const float* mask = (const float*)d_in[4];
    const float* Wq   = (const float*)d_in[5];
    const float* Wk   = (const float*)d_in[6];
    const float* Wv   = (const float*)d_in[7];
    const float* Wp   = (const float*)d_in[8];
    const float* bp   = (const float*)d_in[9];
    float* out = (float*)d_out;

    unsigned short* qhb = (unsigned short*)d_ws;     // bf16 [2,8,1024,64]
    unsigned short* khb = qhb + 1048576;
    unsigned short* vtb = khb + 1048576;             // bf16 [2,8,64,1024]
    float* xpart = (float*)(vtb + 1048576);          // [2][2048][512]
    float* lsump = xpart + 2097152;                  // [2][16384]
    float* xb    = lsump + 32768;                    // [2048][512]

    dim3 gg(32, 8, 1);
    gemm512<0><<<gg, 256, 0, stream>>>(q, Wq, nullptr, nullptr, qhb, 0.125f);
    gemm512<0><<<gg, 256, 0, stream>>>(k, Wk, nullptr, nullptr, khb, 1.0f);
    gemm512<2><<<gg, 256, 0, stream>>>(v, Wv, nullptr, nullptr, vtb, 1.0f);

    attn_mfma<<<256, 512, 0, stream>>>(qhb, khb, vtb, rpb, mask, xpart, lsump);

    combine<<<1024, 256, 0, stream>>>(xpart, lsump, xb);

    gemm512<1><<<gg, 256, 0, stream>>>(xb, Wp, bp, out, nullptr, 1.0f);
}